// Round 2
// baseline (689.784 us; speedup 1.0000x reference)
//
#include <hip/hip_runtime.h>

#define N_NODES   50000
#define N_EDGES   800000
#define IN_CH     128
#define HID       64
#define OUT_CH    64
#define N_CLASSES 10
#define N_GRAPHS  256

// ---------------- degree / dinv ----------------
__global__ __launch_bounds__(256) void deg_kernel(const int* __restrict__ ei,
                                                  float* __restrict__ deg) {
    int e = blockIdx.x * 256 + threadIdx.x;
    if (e >= N_EDGES) return;
    int d = ei[N_EDGES + e];
    atomicAdd(&deg[d], 1.0f);
}

__global__ __launch_bounds__(256) void dinv_kernel(float* __restrict__ deg) {
    int n = blockIdx.x * 256 + threadIdx.x;
    if (n >= N_NODES) return;
    deg[n] = rsqrtf(deg[n] + 1.0f);   // in-place: deg -> dinv
}

// ---------------- fused GEMM + self-loop/bias epilogue ----------------
// X[N,K] @ W[K,64] -> hout[N,64]; agg[N,64] = hout*dinv^2 + b
// RELU applies to the X load (layer-2 input). Safe in-place when X==agg:
// each block's rows are loaded fully into LDS before any global write,
// and blocks only touch their own 16 rows.
template <int K, bool RELU>
__global__ __launch_bounds__(256) void gemm_kernel(
    const float* __restrict__ X, const float* __restrict__ W,
    const float* __restrict__ b, const float* __restrict__ dinv,
    float* __restrict__ hout, float* __restrict__ agg) {
    __shared__ float xs[16][K + 1];
    __shared__ float ws[K][64];
    const int tid = threadIdx.x;
    const int base = blockIdx.x * 16;

    for (int i = tid; i < K * 64; i += 256) (&ws[0][0])[i] = W[i];
    for (int i = tid; i < 16 * K; i += 256) {
        int r = i / K, k = i % K;
        int n = base + r;
        float v = (n < N_NODES) ? X[n * K + k] : 0.0f;
        if (RELU) v = fmaxf(v, 0.0f);
        xs[r][k] = v;
    }
    __syncthreads();

    const int sub = tid >> 4;          // node sub-index 0..15
    const int c0  = (tid & 15) * 4;    // channel group
    const int n   = base + sub;
    float a0 = 0.f, a1 = 0.f, a2 = 0.f, a3 = 0.f;
#pragma unroll 16
    for (int k = 0; k < K; ++k) {
        float xv  = xs[sub][k];
        float4 wv = *reinterpret_cast<const float4*>(&ws[k][c0]);
        a0 += xv * wv.x; a1 += xv * wv.y; a2 += xv * wv.z; a3 += xv * wv.w;
    }
    if (n < N_NODES) {
        float di = dinv[n];
        float dd = di * di;
        float4 bb = *reinterpret_cast<const float4*>(&b[c0]);
        *reinterpret_cast<float4*>(&hout[n * 64 + c0]) =
            make_float4(a0, a1, a2, a3);
        *reinterpret_cast<float4*>(&agg[n * 64 + c0]) =
            make_float4(a0 * dd + bb.x, a1 * dd + bb.y,
                        a2 * dd + bb.z, a3 * dd + bb.w);
    }
}

// ---------------- edge scatter: wave per edge, lane per channel ----------------
__global__ __launch_bounds__(256) void edge_kernel(const int* __restrict__ ei,
                                                   const float* __restrict__ dinv,
                                                   const float* __restrict__ h,
                                                   float* __restrict__ agg) {
    int e = blockIdx.x * 4 + (threadIdx.x >> 6);
    if (e >= N_EDGES) return;
    int lane = threadIdx.x & 63;
    int s = ei[e];
    int d = ei[N_EDGES + e];
    float norm = dinv[s] * dinv[d];
    float v = h[s * 64 + lane] * norm;
    atomicAdd(&agg[d * 64 + lane], v);
}

// ---------------- mean pool (atomic accumulate) ----------------
__global__ __launch_bounds__(256) void pool_kernel(const int* __restrict__ batch,
                                                   const float* __restrict__ h2,
                                                   float* __restrict__ pooled) {
    int n = blockIdx.x * 4 + (threadIdx.x >> 6);
    if (n >= N_NODES) return;
    int lane = threadIdx.x & 63;
    atomicAdd(&pooled[batch[n] * 64 + lane], h2[n * 64 + lane]);
}

__global__ __launch_bounds__(256) void cnt_kernel(const int* __restrict__ batch,
                                                  float* __restrict__ counts) {
    int n = blockIdx.x * 256 + threadIdx.x;
    if (n >= N_NODES) return;
    atomicAdd(&counts[batch[n]], 1.0f);
}

// ---------------- head: (pooled/count) @ Wl + bl ----------------
__global__ __launch_bounds__(256) void head_kernel(const float* __restrict__ pooled,
                                                   const float* __restrict__ counts,
                                                   const float* __restrict__ Wl,
                                                   const float* __restrict__ bl,
                                                   float* __restrict__ out) {
    int gid = blockIdx.x * 256 + threadIdx.x;
    if (gid >= N_GRAPHS * N_CLASSES) return;
    int g = gid / N_CLASSES, c = gid % N_CLASSES;
    float inv = 1.0f / fmaxf(counts[g], 1.0f);
    float acc = 0.f;
#pragma unroll
    for (int k = 0; k < OUT_CH; ++k)
        acc += pooled[g * 64 + k] * Wl[k * N_CLASSES + c];
    out[gid] = acc * inv + bl[c];
}

// ---------------- launch ----------------
extern "C" void kernel_launch(void* const* d_in, const int* in_sizes, int n_in,
                              void* d_out, int out_size, void* d_ws, size_t ws_size,
                              hipStream_t stream) {
    const float* x     = (const float*)d_in[0];
    const int*   ei    = (const int*)d_in[1];
    // d_in[2] = edge_attr (unused by reference)
    const int*   batch = (const int*)d_in[3];
    const float* W1    = (const float*)d_in[4];
    const float* b1    = (const float*)d_in[5];
    const float* W2    = (const float*)d_in[6];
    const float* b2    = (const float*)d_in[7];
    const float* Wl    = (const float*)d_in[8];
    const float* bl    = (const float*)d_in[9];
    float* out = (float*)d_out;

    float* ws     = (float*)d_ws;
    float* deg    = ws;                    // 50048 floats (dinv in-place)
    float* pooled = ws + 50048;            // 16384 floats
    float* counts = ws + 50048 + 16384;    // 256 floats
    float* hA     = ws + 66688;            // 3.2M floats (h_lin, both layers)
    float* aggB   = hA + (size_t)N_NODES * 64;  // 3.2M floats (agg, both layers)

    // zero deg + pooled + counts in one shot
    hipMemsetAsync(ws, 0, (size_t)66688 * sizeof(float), stream);

    deg_kernel <<<(N_EDGES + 255) / 256, 256, 0, stream>>>(ei, deg);
    dinv_kernel<<<(N_NODES + 255) / 256, 256, 0, stream>>>(deg);

    // layer 1: h = x@W1 ; agg = h*dinv^2 + b1 ; edges add
    gemm_kernel<IN_CH, false><<<(N_NODES + 15) / 16, 256, 0, stream>>>(
        x, W1, b1, deg, hA, aggB);
    edge_kernel<<<(N_EDGES + 3) / 4, 256, 0, stream>>>(ei, deg, hA, aggB);

    // layer 2: in-place on aggB (relu on load), h_lin2 -> hA
    gemm_kernel<HID, true><<<(N_NODES + 15) / 16, 256, 0, stream>>>(
        aggB, W2, b2, deg, hA, aggB);
    edge_kernel<<<(N_EDGES + 3) / 4, 256, 0, stream>>>(ei, deg, hA, aggB);

    // pool + head
    pool_kernel<<<(N_NODES + 3) / 4, 256, 0, stream>>>(batch, aggB, pooled);
    cnt_kernel <<<(N_NODES + 255) / 256, 256, 0, stream>>>(batch, counts);
    head_kernel<<<(N_GRAPHS * N_CLASSES + 255) / 256, 256, 0, stream>>>(
        pooled, counts, Wl, bl, out);
}

// Round 3
// 469.418 us; speedup vs baseline: 1.4694x; 1.4694x over previous
//
#include <hip/hip_runtime.h>

#define N_NODES   50000
#define N_EDGES   800000
#define IN_CH     128
#define HID       64
#define OUT_CH    64
#define N_CLASSES 10
#define N_GRAPHS  256

// ---------------- int degree histogram ----------------
__global__ __launch_bounds__(256) void deg_kernel(const int* __restrict__ ei,
                                                  int* __restrict__ cnt) {
    int e = blockIdx.x * 256 + threadIdx.x;
    if (e >= N_EDGES) return;
    atomicAdd(&cnt[ei[N_EDGES + e]], 1);
}

__global__ __launch_bounds__(256) void dinv_kernel(const int* __restrict__ cnt,
                                                   float* __restrict__ dinv) {
    int n = blockIdx.x * 256 + threadIdx.x;
    if (n >= N_NODES) return;
    dinv[n] = rsqrtf((float)cnt[n] + 1.0f);
}

// ---------------- 3-kernel exclusive scan over cnt[N_NODES] ----------------
__global__ __launch_bounds__(256) void scan1_kernel(const int* __restrict__ cnt,
                                                    int* __restrict__ excl,
                                                    int* __restrict__ part) {
    __shared__ int s[256];
    int t = threadIdx.x, i = blockIdx.x * 256 + t;
    int v = (i < N_NODES) ? cnt[i] : 0;
    s[t] = v; __syncthreads();
    for (int off = 1; off < 256; off <<= 1) {
        int x = (t >= off) ? s[t - off] : 0;
        __syncthreads();
        s[t] += x;
        __syncthreads();
    }
    if (i < N_NODES) excl[i] = s[t] - v;
    if (t == 255) part[blockIdx.x] = s[t];
}

__global__ __launch_bounds__(256) void scan2_kernel(int* __restrict__ part,
                                                    int nblk) {
    __shared__ int s[256];
    int t = threadIdx.x;
    int v = (t < nblk) ? part[t] : 0;
    s[t] = v; __syncthreads();
    for (int off = 1; off < 256; off <<= 1) {
        int x = (t >= off) ? s[t - off] : 0;
        __syncthreads();
        s[t] += x;
        __syncthreads();
    }
    if (t < nblk) part[t] = s[t] - v;   // exclusive
}

__global__ __launch_bounds__(256) void scan3_kernel(const int* __restrict__ excl,
                                                    const int* __restrict__ part,
                                                    int* __restrict__ rs,
                                                    int* __restrict__ cur) {
    int i = blockIdx.x * 256 + threadIdx.x;
    if (i >= N_NODES) {
        if (i == N_NODES) rs[N_NODES] = N_EDGES;
        return;
    }
    int v = excl[i] + part[blockIdx.x];
    rs[i] = v;
    cur[i] = v;
}

// ---------------- bucket edges into dst-CSR: pack (src, norm) ----------------
__global__ __launch_bounds__(256) void bucket_kernel(const int* __restrict__ ei,
                                                     const float* __restrict__ dinv,
                                                     int* __restrict__ cur,
                                                     int2* __restrict__ pack) {
    int e = blockIdx.x * 256 + threadIdx.x;
    if (e >= N_EDGES) return;
    int s = ei[e];
    int d = ei[N_EDGES + e];
    float norm = dinv[s] * dinv[d];
    int pos = atomicAdd(&cur[d], 1);
    pack[pos] = make_int2(s, __float_as_int(norm));
}

// ---------------- fused GEMM + self-loop/bias epilogue ----------------
// X[N,K] @ W[K,64] -> hout[N,64]; agg[N,64] = hout*dinv^2 + b
// RELU applies to the X load (layer-2 input). Safe in-place when X==agg.
template <int K, bool RELU>
__global__ __launch_bounds__(256) void gemm_kernel(
    const float* __restrict__ X, const float* __restrict__ W,
    const float* __restrict__ b, const float* __restrict__ dinv,
    float* __restrict__ hout, float* __restrict__ agg) {
    __shared__ float xs[16][K + 1];
    __shared__ float ws[K][64];
    const int tid = threadIdx.x;
    const int base = blockIdx.x * 16;

    for (int i = tid; i < K * 64; i += 256) (&ws[0][0])[i] = W[i];
    for (int i = tid; i < 16 * K; i += 256) {
        int r = i / K, k = i % K;
        int n = base + r;
        float v = (n < N_NODES) ? X[n * K + k] : 0.0f;
        if (RELU) v = fmaxf(v, 0.0f);
        xs[r][k] = v;
    }
    __syncthreads();

    const int sub = tid >> 4;
    const int c0  = (tid & 15) * 4;
    const int n   = base + sub;
    float a0 = 0.f, a1 = 0.f, a2 = 0.f, a3 = 0.f;
#pragma unroll 16
    for (int k = 0; k < K; ++k) {
        float xv  = xs[sub][k];
        float4 wv = *reinterpret_cast<const float4*>(&ws[k][c0]);
        a0 += xv * wv.x; a1 += xv * wv.y; a2 += xv * wv.z; a3 += xv * wv.w;
    }
    if (n < N_NODES) {
        float di = dinv[n];
        float dd = di * di;
        float4 bb = *reinterpret_cast<const float4*>(&b[c0]);
        *reinterpret_cast<float4*>(&hout[n * 64 + c0]) =
            make_float4(a0, a1, a2, a3);
        *reinterpret_cast<float4*>(&agg[n * 64 + c0]) =
            make_float4(a0 * dd + bb.x, a1 * dd + bb.y,
                        a2 * dd + bb.z, a3 * dd + bb.w);
    }
}

// ---------------- CSR gather: wave per dst node, lane per channel ----------------
// agg[n] already holds self-loop + bias; add sum over incident edges, no atomics.
__global__ __launch_bounds__(256) void gather_kernel(const int* __restrict__ rs,
                                                     const int2* __restrict__ pack,
                                                     const float* __restrict__ h,
                                                     float* __restrict__ agg) {
    int n = blockIdx.x * 4 + (threadIdx.x >> 6);
    if (n >= N_NODES) return;
    int lane = threadIdx.x & 63;
    int e   = rs[n];
    int end = rs[n + 1];
    float acc = agg[n * 64 + lane];
    for (; e + 1 < end; e += 2) {
        int2 p0 = pack[e];
        int2 p1 = pack[e + 1];
        float h0 = h[(size_t)p0.x * 64 + lane];
        float h1 = h[(size_t)p1.x * 64 + lane];
        acc += __int_as_float(p0.y) * h0;
        acc += __int_as_float(p1.y) * h1;
    }
    if (e < end) {
        int2 p = pack[e];
        acc += __int_as_float(p.y) * h[(size_t)p.x * 64 + lane];
    }
    agg[n * 64 + lane] = acc;
}

// ---------------- mean pool (atomic accumulate) ----------------
__global__ __launch_bounds__(256) void pool_kernel(const int* __restrict__ batch,
                                                   const float* __restrict__ h2,
                                                   float* __restrict__ pooled) {
    int n = blockIdx.x * 4 + (threadIdx.x >> 6);
    if (n >= N_NODES) return;
    int lane = threadIdx.x & 63;
    atomicAdd(&pooled[batch[n] * 64 + lane], h2[n * 64 + lane]);
}

__global__ __launch_bounds__(256) void cnt_kernel(const int* __restrict__ batch,
                                                  float* __restrict__ counts) {
    int n = blockIdx.x * 256 + threadIdx.x;
    if (n >= N_NODES) return;
    atomicAdd(&counts[batch[n]], 1.0f);
}

// ---------------- head: (pooled/count) @ Wl + bl ----------------
__global__ __launch_bounds__(256) void head_kernel(const float* __restrict__ pooled,
                                                   const float* __restrict__ counts,
                                                   const float* __restrict__ Wl,
                                                   const float* __restrict__ bl,
                                                   float* __restrict__ out) {
    int gid = blockIdx.x * 256 + threadIdx.x;
    if (gid >= N_GRAPHS * N_CLASSES) return;
    int g = gid / N_CLASSES, c = gid % N_CLASSES;
    float inv = 1.0f / fmaxf(counts[g], 1.0f);
    float acc = 0.f;
#pragma unroll
    for (int k = 0; k < OUT_CH; ++k)
        acc += pooled[g * 64 + k] * Wl[k * N_CLASSES + c];
    out[gid] = acc * inv + bl[c];
}

// ---------------- launch ----------------
extern "C" void kernel_launch(void* const* d_in, const int* in_sizes, int n_in,
                              void* d_out, int out_size, void* d_ws, size_t ws_size,
                              hipStream_t stream) {
    const float* x     = (const float*)d_in[0];
    const int*   ei    = (const int*)d_in[1];
    const int*   batch = (const int*)d_in[3];
    const float* W1    = (const float*)d_in[4];
    const float* b1    = (const float*)d_in[5];
    const float* W2    = (const float*)d_in[6];
    const float* b2    = (const float*)d_in[7];
    const float* Wl    = (const float*)d_in[8];
    const float* bl    = (const float*)d_in[9];
    float* out = (float*)d_out;

    // workspace layout (4-byte units)
    int*   wsI    = (int*)d_ws;
    int*   cnt    = wsI;                         // 50048 (zeroed)
    float* pooled = (float*)(wsI + 50048);       // 16384 (zeroed)
    float* counts = (float*)(wsI + 66432);       // 256   (zeroed)
    float* dinv   = (float*)(wsI + 66688);       // 50048
    int*   excl   = wsI + 116736;                // 50048
    int*   part   = wsI + 166784;                // 256
    int*   rs     = wsI + 167040;                // 50064 (N_NODES+1)
    int*   cur    = wsI + 217104;                // 50048
    int2*  pack   = (int2*)(wsI + 267152);       // 800000 int2 (1.6M ints)
    float* hA     = (float*)(wsI + 1867152);     // 3.2M
    float* aggB   = (float*)(wsI + 5067152);     // 3.2M

    const int NBLK = (N_NODES + 255) / 256;      // 196

    hipMemsetAsync(wsI, 0, (size_t)66688 * sizeof(int), stream);

    // degree + dinv + CSR build (once per call)
    deg_kernel  <<<(N_EDGES + 255) / 256, 256, 0, stream>>>(ei, cnt);
    dinv_kernel <<<NBLK, 256, 0, stream>>>(cnt, dinv);
    scan1_kernel<<<NBLK, 256, 0, stream>>>(cnt, excl, part);
    scan2_kernel<<<1, 256, 0, stream>>>(part, NBLK);
    scan3_kernel<<<NBLK + 1, 256, 0, stream>>>(excl, part, rs, cur);
    bucket_kernel<<<(N_EDGES + 255) / 256, 256, 0, stream>>>(ei, dinv, cur, pack);

    // layer 1: h = x@W1 ; agg = h*dinv^2 + b1 ; gather adds neighbors
    gemm_kernel<IN_CH, false><<<(N_NODES + 15) / 16, 256, 0, stream>>>(
        x, W1, b1, dinv, hA, aggB);
    gather_kernel<<<(N_NODES + 3) / 4, 256, 0, stream>>>(rs, pack, hA, aggB);

    // layer 2: in-place on aggB (relu on load), h_lin2 -> hA
    gemm_kernel<HID, true><<<(N_NODES + 15) / 16, 256, 0, stream>>>(
        aggB, W2, b2, dinv, hA, aggB);
    gather_kernel<<<(N_NODES + 3) / 4, 256, 0, stream>>>(rs, pack, hA, aggB);

    // pool + head
    pool_kernel<<<(N_NODES + 3) / 4, 256, 0, stream>>>(batch, aggB, pooled);
    cnt_kernel <<<NBLK, 256, 0, stream>>>(batch, counts);
    head_kernel<<<(N_GRAPHS * N_CLASSES + 255) / 256, 256, 0, stream>>>(
        pooled, counts, Wl, bl, out);
}

// Round 5
// 371.123 us; speedup vs baseline: 1.8586x; 1.2649x over previous
//
#include <hip/hip_runtime.h>

#define N_NODES   50000
#define N_EDGES   800000
#define IN_CH     128
#define HID       64
#define OUT_CH    64
#define N_CLASSES 10
#define N_GRAPHS  256

// ---------------- int degree histogram ----------------
__global__ __launch_bounds__(256) void deg_kernel(const int* __restrict__ ei,
                                                  int* __restrict__ cnt) {
    int e = blockIdx.x * 256 + threadIdx.x;
    if (e >= N_EDGES) return;
    atomicAdd(&cnt[ei[N_EDGES + e]], 1);
}

// ---------------- 3-kernel exclusive scan over cnt[N_NODES] ----------------
__global__ __launch_bounds__(256) void scan1_kernel(const int* __restrict__ cnt,
                                                    int* __restrict__ excl,
                                                    int* __restrict__ part) {
    __shared__ int s[256];
    int t = threadIdx.x, i = blockIdx.x * 256 + t;
    int v = (i < N_NODES) ? cnt[i] : 0;
    s[t] = v; __syncthreads();
    for (int off = 1; off < 256; off <<= 1) {
        int x = (t >= off) ? s[t - off] : 0;
        __syncthreads();
        s[t] += x;
        __syncthreads();
    }
    if (i < N_NODES) excl[i] = s[t] - v;
    if (t == 255) part[blockIdx.x] = s[t];
}

__global__ __launch_bounds__(256) void scan2_kernel(int* __restrict__ part,
                                                    int nblk) {
    __shared__ int s[256];
    int t = threadIdx.x;
    int v = (t < nblk) ? part[t] : 0;
    s[t] = v; __syncthreads();
    for (int off = 1; off < 256; off <<= 1) {
        int x = (t >= off) ? s[t - off] : 0;
        __syncthreads();
        s[t] += x;
        __syncthreads();
    }
    if (t < nblk) part[t] = s[t] - v;   // exclusive
}

// scan3 + fused dinv
__global__ __launch_bounds__(256) void scan3_kernel(const int* __restrict__ excl,
                                                    const int* __restrict__ part,
                                                    const int* __restrict__ cnt,
                                                    int* __restrict__ rs,
                                                    int* __restrict__ cur,
                                                    float* __restrict__ dinv) {
    int i = blockIdx.x * 256 + threadIdx.x;
    if (i >= N_NODES) {
        if (i == N_NODES) rs[N_NODES] = N_EDGES;
        return;
    }
    int v = excl[i] + part[blockIdx.x];
    rs[i] = v;
    cur[i] = v;
    dinv[i] = rsqrtf((float)cnt[i] + 1.0f);
}

// ---------------- bucket edges into dst-CSR: pack (src, norm) ----------------
__global__ __launch_bounds__(256) void bucket_kernel(const int* __restrict__ ei,
                                                     const float* __restrict__ dinv,
                                                     int* __restrict__ cur,
                                                     int2* __restrict__ pack) {
    int e = blockIdx.x * 256 + threadIdx.x;
    if (e >= N_EDGES) return;
    int s = ei[e];
    int d = ei[N_EDGES + e];
    float norm = dinv[s] * dinv[d];
    int pos = atomicAdd(&cur[d], 1);
    pack[pos] = make_int2(s, __float_as_int(norm));
}

// ---------------- fused GEMM + self-loop/bias epilogue ----------------
// X[N,K] @ W[K,64] -> hout[N,64]; agg[N,64] = hout*dinv^2 + b
// RELU applies to the X load (layer-2 input). Safe in-place when X==agg.
template <int K, bool RELU>
__global__ __launch_bounds__(256) void gemm_kernel(
    const float* __restrict__ X, const float* __restrict__ W,
    const float* __restrict__ b, const float* __restrict__ dinv,
    float* __restrict__ hout, float* __restrict__ agg) {
    __shared__ float xs[16][K + 1];
    __shared__ float ws[K][64];
    const int tid = threadIdx.x;
    const int base = blockIdx.x * 16;

    for (int i = tid; i < K * 64; i += 256) (&ws[0][0])[i] = W[i];
    for (int i = tid; i < 16 * K; i += 256) {
        int r = i / K, k = i % K;
        int n = base + r;
        float v = (n < N_NODES) ? X[n * K + k] : 0.0f;
        if (RELU) v = fmaxf(v, 0.0f);
        xs[r][k] = v;
    }
    __syncthreads();

    const int sub = tid >> 4;
    const int c0  = (tid & 15) * 4;
    const int n   = base + sub;
    float a0 = 0.f, a1 = 0.f, a2 = 0.f, a3 = 0.f;
#pragma unroll 16
    for (int k = 0; k < K; ++k) {
        float xv  = xs[sub][k];
        float4 wv = *reinterpret_cast<const float4*>(&ws[k][c0]);
        a0 += xv * wv.x; a1 += xv * wv.y; a2 += xv * wv.z; a3 += xv * wv.w;
    }
    if (n < N_NODES) {
        float di = dinv[n];
        float dd = di * di;
        float4 bb = *reinterpret_cast<const float4*>(&b[c0]);
        *reinterpret_cast<float4*>(&hout[n * 64 + c0]) =
            make_float4(a0, a1, a2, a3);
        *reinterpret_cast<float4*>(&agg[n * 64 + c0]) =
            make_float4(a0 * dd + bb.x, a1 * dd + bb.y,
                        a2 * dd + bb.z, a3 * dd + bb.w);
    }
}

// ---------------- CSR gather: wave per dst node, lane per channel ----------------
// agg[n] already holds self-loop + bias; add sum over incident edges, no atomics.
__global__ __launch_bounds__(256) void gather_kernel(const int* __restrict__ rs,
                                                     const int2* __restrict__ pack,
                                                     const float* __restrict__ h,
                                                     float* __restrict__ agg) {
    int n = blockIdx.x * 4 + (threadIdx.x >> 6);
    if (n >= N_NODES) return;
    int lane = threadIdx.x & 63;
    int e   = rs[n];
    int end = rs[n + 1];
    float acc = agg[n * 64 + lane];
    for (; e + 3 < end; e += 4) {
        int2 p0 = pack[e];
        int2 p1 = pack[e + 1];
        int2 p2 = pack[e + 2];
        int2 p3 = pack[e + 3];
        float h0 = h[(size_t)p0.x * 64 + lane];
        float h1 = h[(size_t)p1.x * 64 + lane];
        float h2 = h[(size_t)p2.x * 64 + lane];
        float h3 = h[(size_t)p3.x * 64 + lane];
        acc += __int_as_float(p0.y) * h0;
        acc += __int_as_float(p1.y) * h1;
        acc += __int_as_float(p2.y) * h2;
        acc += __int_as_float(p3.y) * h3;
    }
    for (; e < end; ++e) {
        int2 p = pack[e];
        acc += __int_as_float(p.y) * h[(size_t)p.x * 64 + lane];
    }
    agg[n * 64 + lane] = acc;
}

// ---------------- mean pool: sorted-run register accumulation ----------------
// block = 4 waves; each wave owns 64 consecutive nodes, lane = channel.
// One atomicAdd per (graph-run, lane) instead of per (node, lane).
__global__ __launch_bounds__(256) void pool_kernel(const int* __restrict__ batch,
                                                   const float* __restrict__ h2,
                                                   float* __restrict__ pooled) {
    int wave = threadIdx.x >> 6;
    int lane = threadIdx.x & 63;
    int base = blockIdx.x * 256 + wave * 64;
    if (base >= N_NODES) return;
    int endn = base + 64;
    if (endn > N_NODES) endn = N_NODES;
    int curg = batch[base];
    float acc = 0.0f;
    for (int n = base; n < endn; ++n) {
        int g = batch[n];
        if (g != curg) {
            atomicAdd(&pooled[curg * 64 + lane], acc);
            acc = 0.0f;
            curg = g;
        }
        acc += h2[(size_t)n * 64 + lane];
    }
    atomicAdd(&pooled[curg * 64 + lane], acc);
}

// ---------------- graph boundaries (batch sorted): start[g] per graph ----------------
__global__ __launch_bounds__(256) void bound_kernel(const int* __restrict__ batch,
                                                    int* __restrict__ start) {
    int n = blockIdx.x * 256 + threadIdx.x;
    if (n >= N_NODES) return;
    int cur  = batch[n];
    int prev = (n == 0) ? -1 : batch[n - 1];
    for (int g = prev + 1; g <= cur; ++g) start[g] = n;
    if (n == N_NODES - 1)
        for (int g = cur + 1; g <= N_GRAPHS; ++g) start[g] = N_NODES;
}

// ---------------- head: (pooled/count) @ Wl + bl ----------------
__global__ __launch_bounds__(256) void head_kernel(const float* __restrict__ pooled,
                                                   const int* __restrict__ start,
                                                   const float* __restrict__ Wl,
                                                   const float* __restrict__ bl,
                                                   float* __restrict__ out) {
    int gid = blockIdx.x * 256 + threadIdx.x;
    if (gid >= N_GRAPHS * N_CLASSES) return;
    int g = gid / N_CLASSES, c = gid % N_CLASSES;
    float cntf = (float)(start[g + 1] - start[g]);
    float inv = 1.0f / fmaxf(cntf, 1.0f);
    float acc = 0.f;
#pragma unroll
    for (int k = 0; k < OUT_CH; ++k)
        acc += pooled[g * 64 + k] * Wl[k * N_CLASSES + c];
    out[gid] = acc * inv + bl[c];
}

// ---------------- launch ----------------
extern "C" void kernel_launch(void* const* d_in, const int* in_sizes, int n_in,
                              void* d_out, int out_size, void* d_ws, size_t ws_size,
                              hipStream_t stream) {
    const float* x     = (const float*)d_in[0];
    const int*   ei    = (const int*)d_in[1];
    const int*   batch = (const int*)d_in[3];
    const float* W1    = (const float*)d_in[4];
    const float* b1    = (const float*)d_in[5];
    const float* W2    = (const float*)d_in[6];
    const float* b2    = (const float*)d_in[7];
    const float* Wl    = (const float*)d_in[8];
    const float* bl    = (const float*)d_in[9];
    float* out = (float*)d_out;

    // workspace layout (4-byte units)
    int*   wsI    = (int*)d_ws;
    int*   cnt    = wsI;                         // 50048 (zeroed)
    float* pooled = (float*)(wsI + 50048);       // 16384 (zeroed)
    int*   start  = wsI + 66432;                 // 257
    float* dinv   = (float*)(wsI + 66689 + 63);  // align-ish; 50048
    int*   excl   = wsI + 116800;                // 50048
    int*   part   = wsI + 166848;                // 256
    int*   rs     = wsI + 167104;                // 50064 (N_NODES+1)
    int*   cur    = wsI + 217168;                // 50048
    int2*  pack   = (int2*)(wsI + 267216);       // 800000 int2 (1.6M ints)
    float* hA     = (float*)(wsI + 1867216);     // 3.2M
    float* aggB   = (float*)(wsI + 5067216);     // 3.2M

    const int NBLK = (N_NODES + 255) / 256;      // 196

    // zero cnt + pooled (start needs no zeroing; bound_kernel fills all 257)
    hipMemsetAsync(wsI, 0, (size_t)66432 * sizeof(int), stream);

    // degree + CSR build (once per call; same work every call)
    deg_kernel  <<<(N_EDGES + 255) / 256, 256, 0, stream>>>(ei, cnt);
    scan1_kernel<<<NBLK, 256, 0, stream>>>(cnt, excl, part);
    scan2_kernel<<<1, 256, 0, stream>>>(part, NBLK);
    scan3_kernel<<<NBLK + 1, 256, 0, stream>>>(excl, part, cnt, rs, cur, dinv);
    bucket_kernel<<<(N_EDGES + 255) / 256, 256, 0, stream>>>(ei, dinv, cur, pack);

    // layer 1: h = x@W1 ; agg = h*dinv^2 + b1 ; gather adds neighbors
    gemm_kernel<IN_CH, false><<<(N_NODES + 15) / 16, 256, 0, stream>>>(
        x, W1, b1, dinv, hA, aggB);
    gather_kernel<<<(N_NODES + 3) / 4, 256, 0, stream>>>(rs, pack, hA, aggB);

    // layer 2: in-place on aggB (relu on load), h_lin2 -> hA
    gemm_kernel<HID, true><<<(N_NODES + 15) / 16, 256, 0, stream>>>(
        aggB, W2, b2, dinv, hA, aggB);
    gather_kernel<<<(N_NODES + 3) / 4, 256, 0, stream>>>(rs, pack, hA, aggB);

    // pool + boundaries + head
    pool_kernel <<<NBLK, 256, 0, stream>>>(batch, aggB, pooled);
    bound_kernel<<<NBLK, 256, 0, stream>>>(batch, start);
    head_kernel <<<(N_GRAPHS * N_CLASSES + 255) / 256, 256, 0, stream>>>(
        pooled, start, Wl, bl, out);
}

// Round 7
// 357.016 us; speedup vs baseline: 1.9321x; 1.0395x over previous
//
#include <hip/hip_runtime.h>

#define N_NODES   50000
#define N_EDGES   800000
#define IN_CH     128
#define HID       64
#define OUT_CH    64
#define N_CLASSES 10
#define N_GRAPHS  256

// ---------------- int degree histogram ----------------
__global__ __launch_bounds__(256) void deg_kernel(const int* __restrict__ ei,
                                                  int* __restrict__ cnt) {
    int e = blockIdx.x * 256 + threadIdx.x;
    if (e >= N_EDGES) return;
    atomicAdd(&cnt[ei[N_EDGES + e]], 1);
}

// ---------------- 3-kernel exclusive scan over cnt[N_NODES] ----------------
__global__ __launch_bounds__(256) void scan1_kernel(const int* __restrict__ cnt,
                                                    int* __restrict__ excl,
                                                    int* __restrict__ part) {
    __shared__ int s[256];
    int t = threadIdx.x, i = blockIdx.x * 256 + t;
    int v = (i < N_NODES) ? cnt[i] : 0;
    s[t] = v; __syncthreads();
    for (int off = 1; off < 256; off <<= 1) {
        int x = (t >= off) ? s[t - off] : 0;
        __syncthreads();
        s[t] += x;
        __syncthreads();
    }
    if (i < N_NODES) excl[i] = s[t] - v;
    if (t == 255) part[blockIdx.x] = s[t];
}

__global__ __launch_bounds__(256) void scan2_kernel(int* __restrict__ part,
                                                    int nblk) {
    __shared__ int s[256];
    int t = threadIdx.x;
    int v = (t < nblk) ? part[t] : 0;
    s[t] = v; __syncthreads();
    for (int off = 1; off < 256; off <<= 1) {
        int x = (t >= off) ? s[t - off] : 0;
        __syncthreads();
        s[t] += x;
        __syncthreads();
    }
    if (t < nblk) part[t] = s[t] - v;   // exclusive
}

// scan3 + fused dinv
__global__ __launch_bounds__(256) void scan3_kernel(const int* __restrict__ excl,
                                                    const int* __restrict__ part,
                                                    const int* __restrict__ cnt,
                                                    int* __restrict__ rs,
                                                    int* __restrict__ cur,
                                                    float* __restrict__ dinv) {
    int i = blockIdx.x * 256 + threadIdx.x;
    if (i >= N_NODES) {
        if (i == N_NODES) rs[N_NODES] = N_EDGES;
        return;
    }
    int v = excl[i] + part[blockIdx.x];
    rs[i] = v;
    cur[i] = v;
    dinv[i] = rsqrtf((float)cnt[i] + 1.0f);
}

// ---------------- bucket edges into dst-CSR: pack src only (4 B) ----------------
__global__ __launch_bounds__(256) void bucket_kernel(const int* __restrict__ ei,
                                                     int* __restrict__ cur,
                                                     int* __restrict__ pack) {
    int e = blockIdx.x * 256 + threadIdx.x;
    if (e >= N_EDGES) return;
    int s = ei[e];
    int d = ei[N_EDGES + e];
    int pos = atomicAdd(&cur[d], 1);
    pack[pos] = s;
}

// ---------------- GEMM1: hs1 = (x @ W1) * dinv ----------------
__global__ __launch_bounds__(256) void gemm1_kernel(
    const float* __restrict__ X, const float* __restrict__ W,
    const float* __restrict__ dinv, float* __restrict__ hs) {
    __shared__ float xs[16][IN_CH + 1];
    __shared__ float ws[IN_CH][64];
    const int tid = threadIdx.x;
    const int base = blockIdx.x * 16;

    for (int i = tid; i < IN_CH * 64; i += 256) (&ws[0][0])[i] = W[i];
    for (int i = tid; i < 16 * IN_CH; i += 256) {
        int r = i / IN_CH, k = i % IN_CH;
        xs[r][k] = X[(size_t)(base + r) * IN_CH + k];
    }
    __syncthreads();

    const int sub = tid >> 4;
    const int c0  = (tid & 15) * 4;
    const int n   = base + sub;
    float a0 = 0.f, a1 = 0.f, a2 = 0.f, a3 = 0.f;
#pragma unroll 16
    for (int k = 0; k < IN_CH; ++k) {
        float xv  = xs[sub][k];
        float4 wv = *reinterpret_cast<const float4*>(&ws[k][c0]);
        a0 += xv * wv.x; a1 += xv * wv.y; a2 += xv * wv.z; a3 += xv * wv.w;
    }
    float di = dinv[n];
    *reinterpret_cast<float4*>(&hs[(size_t)n * 64 + c0]) =
        make_float4(a0 * di, a1 * di, a2 * di, a3 * di);
}

// ---------------- fused gather1 + GEMM2 ----------------
// stage: xs[r] = relu(dinv[n]*(hs1[n] + sum_{src in CSR(n)} hs1[src]) + b1)
// then:  hs2 = (xs @ W2) * dinv
__global__ __launch_bounds__(256) void gemmgather2_kernel(
    const int* __restrict__ rs, const int* __restrict__ pack,
    const float* __restrict__ hs1, const float* __restrict__ dinv,
    const float* __restrict__ W2, const float* __restrict__ b1,
    float* __restrict__ hs2) {
    __shared__ float xs[16][64];
    __shared__ float ws[64][64];
    const int tid  = threadIdx.x;
    const int base = blockIdx.x * 16;
    const int wave = tid >> 6;
    const int lane = tid & 63;

    for (int i = tid; i < 64 * 64; i += 256) (&ws[0][0])[i] = W2[i];

    const float bb = b1[lane];
    for (int r = wave * 4; r < wave * 4 + 4; ++r) {
        int n = base + r;
        float own = hs1[(size_t)n * 64 + lane];
        float di  = dinv[n];
        int e = rs[n], end = rs[n + 1];
        float acc = 0.f;
        for (; e + 3 < end; e += 4) {
            int s0 = pack[e], s1 = pack[e + 1], s2 = pack[e + 2], s3 = pack[e + 3];
            float h0 = hs1[(size_t)s0 * 64 + lane];
            float h1 = hs1[(size_t)s1 * 64 + lane];
            float h2 = hs1[(size_t)s2 * 64 + lane];
            float h3 = hs1[(size_t)s3 * 64 + lane];
            acc += h0 + h1 + h2 + h3;
        }
        for (; e < end; ++e)
            acc += hs1[(size_t)pack[e] * 64 + lane];
        xs[r][lane] = fmaxf(di * (own + acc) + bb, 0.f);
    }
    __syncthreads();

    const int sub = tid >> 4;
    const int c0  = (tid & 15) * 4;
    const int n   = base + sub;
    float a0 = 0.f, a1 = 0.f, a2 = 0.f, a3 = 0.f;
#pragma unroll 16
    for (int k = 0; k < 64; ++k) {
        float xv  = xs[sub][k];
        float4 wv = *reinterpret_cast<const float4*>(&ws[k][c0]);
        a0 += xv * wv.x; a1 += xv * wv.y; a2 += xv * wv.z; a3 += xv * wv.w;
    }
    float di = dinv[n];
    *reinterpret_cast<float4*>(&hs2[(size_t)n * 64 + c0]) =
        make_float4(a0 * di, a1 * di, a2 * di, a3 * di);
}

// ---------------- fused gather2 + mean-pool accumulate ----------------
// agg2[n] = dinv[n]*(hs2[n] + sum hs2[src]) + b2 ; run-reduce by sorted batch id.
__global__ __launch_bounds__(256) void gatherpool_kernel(
    const int* __restrict__ rs, const int* __restrict__ pack,
    const float* __restrict__ hs2, const float* __restrict__ dinv,
    const float* __restrict__ b2, const int* __restrict__ batch,
    float* __restrict__ pooled) {
    int wave = threadIdx.x >> 6;
    int lane = threadIdx.x & 63;
    int base = blockIdx.x * 64 + wave * 16;
    if (base >= N_NODES) return;
    int endn = base + 16;
    if (endn > N_NODES) endn = N_NODES;
    const float bb = b2[lane];
    int curg = batch[base];
    float racc = 0.f;
    for (int n = base; n < endn; ++n) {
        float own = hs2[(size_t)n * 64 + lane];
        float di  = dinv[n];
        int e = rs[n], end = rs[n + 1];
        float acc = 0.f;
        for (; e + 3 < end; e += 4) {
            int s0 = pack[e], s1 = pack[e + 1], s2 = pack[e + 2], s3 = pack[e + 3];
            float h0 = hs2[(size_t)s0 * 64 + lane];
            float h1 = hs2[(size_t)s1 * 64 + lane];
            float h2 = hs2[(size_t)s2 * 64 + lane];
            float h3 = hs2[(size_t)s3 * 64 + lane];
            acc += h0 + h1 + h2 + h3;
        }
        for (; e < end; ++e)
            acc += hs2[(size_t)pack[e] * 64 + lane];
        float val = di * (own + acc) + bb;
        int g = batch[n];
        if (g != curg) {
            atomicAdd(&pooled[curg * 64 + lane], racc);
            racc = 0.f;
            curg = g;
        }
        racc += val;
    }
    atomicAdd(&pooled[curg * 64 + lane], racc);
}

// ---------------- graph boundaries (batch sorted): start[g] per graph ----------------
__global__ __launch_bounds__(256) void bound_kernel(const int* __restrict__ batch,
                                                    int* __restrict__ start) {
    int n = blockIdx.x * 256 + threadIdx.x;
    if (n >= N_NODES) return;
    int cur  = batch[n];
    int prev = (n == 0) ? -1 : batch[n - 1];
    for (int g = prev + 1; g <= cur; ++g) start[g] = n;
    if (n == N_NODES - 1)
        for (int g = cur + 1; g <= N_GRAPHS; ++g) start[g] = N_NODES;
}

// ---------------- head: (pooled/count) @ Wl + bl ----------------
__global__ __launch_bounds__(256) void head_kernel(const float* __restrict__ pooled,
                                                   const int* __restrict__ start,
                                                   const float* __restrict__ Wl,
                                                   const float* __restrict__ bl,
                                                   float* __restrict__ out) {
    int gid = blockIdx.x * 256 + threadIdx.x;
    if (gid >= N_GRAPHS * N_CLASSES) return;
    int g = gid / N_CLASSES, c = gid % N_CLASSES;
    float cntf = (float)(start[g + 1] - start[g]);
    float inv = 1.0f / fmaxf(cntf, 1.0f);
    float acc = 0.f;
#pragma unroll
    for (int k = 0; k < OUT_CH; ++k)
        acc += pooled[g * 64 + k] * Wl[k * N_CLASSES + c];
    out[gid] = acc * inv + bl[c];
}

// ---------------- launch ----------------
extern "C" void kernel_launch(void* const* d_in, const int* in_sizes, int n_in,
                              void* d_out, int out_size, void* d_ws, size_t ws_size,
                              hipStream_t stream) {
    const float* x     = (const float*)d_in[0];
    const int*   ei    = (const int*)d_in[1];
    const int*   batch = (const int*)d_in[3];
    const float* W1    = (const float*)d_in[4];
    const float* b1    = (const float*)d_in[5];
    const float* W2    = (const float*)d_in[6];
    const float* b2    = (const float*)d_in[7];
    const float* Wl    = (const float*)d_in[8];
    const float* bl    = (const float*)d_in[9];
    float* out = (float*)d_out;

    // workspace layout (4-byte units)
    int*   wsI    = (int*)d_ws;
    int*   cnt    = wsI;                         // [0, 50048)  zeroed
    float* pooled = (float*)(wsI + 50048);       // [50048, 66432) zeroed
    int*   start  = wsI + 66432;                 // [66432, 66689)
    float* dinv   = (float*)(wsI + 66752);       // [66752, 116800)
    int*   excl   = wsI + 116800;                // [116800, 166848)
    int*   part   = wsI + 166848;                // [166848, 167104)
    int*   rs     = wsI + 167104;                // [167104, 217168) N_NODES+1
    int*   cur    = wsI + 217168;                // [217168, 267216)
    int*   pack   = wsI + 267216;                // [267216, 1067216) 800000 ints
    float* hs1    = (float*)(wsI + 1067216);     // 3.2M floats
    float* hs2    = (float*)(wsI + 4267216);     // 3.2M floats
    // total 7,467,216 ints ~= 29.9 MB

    const int NBLK = (N_NODES + 255) / 256;      // 196

    // zero cnt + pooled
    hipMemsetAsync(wsI, 0, (size_t)66432 * sizeof(int), stream);

    // degree + CSR build (same work every call)
    deg_kernel   <<<(N_EDGES + 255) / 256, 256, 0, stream>>>(ei, cnt);
    scan1_kernel <<<NBLK, 256, 0, stream>>>(cnt, excl, part);
    scan2_kernel <<<1, 256, 0, stream>>>(part, NBLK);
    scan3_kernel <<<NBLK + 1, 256, 0, stream>>>(excl, part, cnt, rs, cur, dinv);
    bucket_kernel<<<(N_EDGES + 255) / 256, 256, 0, stream>>>(ei, cur, pack);

    // layer 1 GEMM (hs1 = x@W1 * dinv)   [50000 = 3125 * 16 exactly]
    gemm1_kernel<<<N_NODES / 16, 256, 0, stream>>>(x, W1, dinv, hs1);

    // layer 1 gather fused into layer 2 GEMM (hs2 = relu(agg1)@W2 * dinv)
    gemmgather2_kernel<<<N_NODES / 16, 256, 0, stream>>>(
        rs, pack, hs1, dinv, W2, b1, hs2);

    // layer 2 gather fused with mean-pool accumulation
    gatherpool_kernel<<<(N_NODES + 63) / 64, 256, 0, stream>>>(
        rs, pack, hs2, dinv, b2, batch, pooled);

    // boundaries + head
    bound_kernel<<<NBLK, 256, 0, stream>>>(batch, start);
    head_kernel <<<(N_GRAPHS * N_CLASSES + 255) / 256, 256, 0, stream>>>(
        pooled, start, Wl, bl, out);
}

// Round 9
// 320.997 us; speedup vs baseline: 2.1489x; 1.1122x over previous
//
#include <hip/hip_runtime.h>

#define N_NODES   50000
#define N_EDGES   800000
#define IN_CH     128
#define HID       64
#define OUT_CH    64
#define N_CLASSES 10
#define N_GRAPHS  256

// ---------------- int degree histogram ----------------
__global__ __launch_bounds__(256) void deg_kernel(const int* __restrict__ ei,
                                                  int* __restrict__ cnt) {
    int e = blockIdx.x * 256 + threadIdx.x;
    if (e >= N_EDGES) return;
    atomicAdd(&cnt[ei[N_EDGES + e]], 1);
}

// ---------------- 3-kernel exclusive scan over cnt[N_NODES] ----------------
__global__ __launch_bounds__(256) void scan1_kernel(const int* __restrict__ cnt,
                                                    int* __restrict__ excl,
                                                    int* __restrict__ part) {
    __shared__ int s[256];
    int t = threadIdx.x, i = blockIdx.x * 256 + t;
    int v = (i < N_NODES) ? cnt[i] : 0;
    s[t] = v; __syncthreads();
    for (int off = 1; off < 256; off <<= 1) {
        int x = (t >= off) ? s[t - off] : 0;
        __syncthreads();
        s[t] += x;
        __syncthreads();
    }
    if (i < N_NODES) excl[i] = s[t] - v;
    if (t == 255) part[blockIdx.x] = s[t];
}

__global__ __launch_bounds__(256) void scan2_kernel(int* __restrict__ part,
                                                    int nblk) {
    __shared__ int s[256];
    int t = threadIdx.x;
    int v = (t < nblk) ? part[t] : 0;
    s[t] = v; __syncthreads();
    for (int off = 1; off < 256; off <<= 1) {
        int x = (t >= off) ? s[t - off] : 0;
        __syncthreads();
        s[t] += x;
        __syncthreads();
    }
    if (t < nblk) part[t] = s[t] - v;   // exclusive
}

// scan3 + fused dinv
__global__ __launch_bounds__(256) void scan3_kernel(const int* __restrict__ excl,
                                                    const int* __restrict__ part,
                                                    const int* __restrict__ cnt,
                                                    int* __restrict__ rs,
                                                    int* __restrict__ cur,
                                                    float* __restrict__ dinv) {
    int i = blockIdx.x * 256 + threadIdx.x;
    if (i >= N_NODES) {
        if (i == N_NODES) rs[N_NODES] = N_EDGES;
        return;
    }
    int v = excl[i] + part[blockIdx.x];
    rs[i] = v;
    cur[i] = v;
    dinv[i] = rsqrtf((float)cnt[i] + 1.0f);
}

// ---------------- bucket edges into dst-CSR: pack src only (4 B) ----------------
__global__ __launch_bounds__(256) void bucket_kernel(const int* __restrict__ ei,
                                                     int* __restrict__ cur,
                                                     int* __restrict__ pack) {
    int e = blockIdx.x * 256 + threadIdx.x;
    if (e >= N_EDGES) return;
    int s = ei[e];
    int d = ei[N_EDGES + e];
    int pos = atomicAdd(&cur[d], 1);
    pack[pos] = s;
}

// ---------------- GEMM1: hs1 = (x @ W1) * dinv ----------------
__global__ __launch_bounds__(256) void gemm1_kernel(
    const float* __restrict__ X, const float* __restrict__ W,
    const float* __restrict__ dinv, float* __restrict__ hs) {
    __shared__ float xs[16][IN_CH + 1];
    __shared__ float ws[IN_CH][64];
    const int tid = threadIdx.x;
    const int base = blockIdx.x * 16;

    for (int i = tid; i < IN_CH * 64; i += 256) (&ws[0][0])[i] = W[i];
    for (int i = tid; i < 16 * IN_CH; i += 256) {
        int r = i / IN_CH, k = i % IN_CH;
        xs[r][k] = X[(size_t)(base + r) * IN_CH + k];
    }
    __syncthreads();

    const int sub = tid >> 4;
    const int c0  = (tid & 15) * 4;
    const int n   = base + sub;
    float a0 = 0.f, a1 = 0.f, a2 = 0.f, a3 = 0.f;
#pragma unroll 16
    for (int k = 0; k < IN_CH; ++k) {
        float xv  = xs[sub][k];
        float4 wv = *reinterpret_cast<const float4*>(&ws[k][c0]);
        a0 += xv * wv.x; a1 += xv * wv.y; a2 += xv * wv.z; a3 += xv * wv.w;
    }
    float di = dinv[n];
    *reinterpret_cast<float4*>(&hs[(size_t)n * 64 + c0]) =
        make_float4(a0 * di, a1 * di, a2 * di, a3 * di);
}

// ---------------- fused gather1 + GEMM2 ----------------
// stage: xs[r] = relu(dinv[n]*(hs1[n] + sum_{src in CSR(n)} hs1[src]) + b1)
// then:  hs2 = (xs @ W2) * dinv
__global__ __launch_bounds__(256) void gemmgather2_kernel(
    const int* __restrict__ rs, const int* __restrict__ pack,
    const float* __restrict__ hs1, const float* __restrict__ dinv,
    const float* __restrict__ W2, const float* __restrict__ b1,
    float* __restrict__ hs2) {
    __shared__ float xs[16][64];
    __shared__ float ws[64][64];
    const int tid  = threadIdx.x;
    const int base = blockIdx.x * 16;
    const int wave = tid >> 6;
    const int lane = tid & 63;

    for (int i = tid; i < 64 * 64; i += 256) (&ws[0][0])[i] = W2[i];

    const float bb = b1[lane];
    for (int r = wave * 4; r < wave * 4 + 4; ++r) {
        int n = base + r;
        float own = hs1[(size_t)n * 64 + lane];
        float di  = dinv[n];
        int e = rs[n], end = rs[n + 1];
        float acc = 0.f;
        for (; e + 7 < end; e += 8) {
            int s0 = pack[e],     s1 = pack[e + 1], s2 = pack[e + 2], s3 = pack[e + 3];
            int s4 = pack[e + 4], s5 = pack[e + 5], s6 = pack[e + 6], s7 = pack[e + 7];
            float h0 = hs1[(size_t)s0 * 64 + lane];
            float h1 = hs1[(size_t)s1 * 64 + lane];
            float h2 = hs1[(size_t)s2 * 64 + lane];
            float h3 = hs1[(size_t)s3 * 64 + lane];
            float h4 = hs1[(size_t)s4 * 64 + lane];
            float h5 = hs1[(size_t)s5 * 64 + lane];
            float h6 = hs1[(size_t)s6 * 64 + lane];
            float h7 = hs1[(size_t)s7 * 64 + lane];
            acc += ((h0 + h1) + (h2 + h3)) + ((h4 + h5) + (h6 + h7));
        }
        for (; e + 3 < end; e += 4) {
            int s0 = pack[e], s1 = pack[e + 1], s2 = pack[e + 2], s3 = pack[e + 3];
            float h0 = hs1[(size_t)s0 * 64 + lane];
            float h1 = hs1[(size_t)s1 * 64 + lane];
            float h2 = hs1[(size_t)s2 * 64 + lane];
            float h3 = hs1[(size_t)s3 * 64 + lane];
            acc += (h0 + h1) + (h2 + h3);
        }
        for (; e < end; ++e)
            acc += hs1[(size_t)pack[e] * 64 + lane];
        xs[r][lane] = fmaxf(di * (own + acc) + bb, 0.f);
    }
    __syncthreads();

    const int sub = tid >> 4;
    const int c0  = (tid & 15) * 4;
    const int n   = base + sub;
    float a0 = 0.f, a1 = 0.f, a2 = 0.f, a3 = 0.f;
#pragma unroll 16
    for (int k = 0; k < 64; ++k) {
        float xv  = xs[sub][k];
        float4 wv = *reinterpret_cast<const float4*>(&ws[k][c0]);
        a0 += xv * wv.x; a1 += xv * wv.y; a2 += xv * wv.z; a3 += xv * wv.w;
    }
    float di = dinv[n];
    *reinterpret_cast<float4*>(&hs2[(size_t)n * 64 + c0]) =
        make_float4(a0 * di, a1 * di, a2 * di, a3 * di);
}

// ---------------- fused gather2 + mean-pool accumulate ----------------
// 4 nodes per wave (grid 3125 blocks -> ~32 waves/CU) for latency hiding.
// agg2[n] = dinv[n]*(hs2[n] + sum hs2[src]) + b2 ; run-reduce by sorted batch id.
__global__ __launch_bounds__(256) void gatherpool_kernel(
    const int* __restrict__ rs, const int* __restrict__ pack,
    const float* __restrict__ hs2, const float* __restrict__ dinv,
    const float* __restrict__ b2, const int* __restrict__ batch,
    float* __restrict__ pooled) {
    int wave = threadIdx.x >> 6;
    int lane = threadIdx.x & 63;
    int base = blockIdx.x * 16 + wave * 4;
    if (base >= N_NODES) return;
    int endn = base + 4;
    if (endn > N_NODES) endn = N_NODES;
    const float bb = b2[lane];
    int curg = batch[base];
    float racc = 0.f;
    for (int n = base; n < endn; ++n) {
        float own = hs2[(size_t)n * 64 + lane];
        float di  = dinv[n];
        int e = rs[n], end = rs[n + 1];
        float acc = 0.f;
        for (; e + 7 < end; e += 8) {
            int s0 = pack[e],     s1 = pack[e + 1], s2 = pack[e + 2], s3 = pack[e + 3];
            int s4 = pack[e + 4], s5 = pack[e + 5], s6 = pack[e + 6], s7 = pack[e + 7];
            float h0 = hs2[(size_t)s0 * 64 + lane];
            float h1 = hs2[(size_t)s1 * 64 + lane];
            float h2 = hs2[(size_t)s2 * 64 + lane];
            float h3 = hs2[(size_t)s3 * 64 + lane];
            float h4 = hs2[(size_t)s4 * 64 + lane];
            float h5 = hs2[(size_t)s5 * 64 + lane];
            float h6 = hs2[(size_t)s6 * 64 + lane];
            float h7 = hs2[(size_t)s7 * 64 + lane];
            acc += ((h0 + h1) + (h2 + h3)) + ((h4 + h5) + (h6 + h7));
        }
        for (; e + 3 < end; e += 4) {
            int s0 = pack[e], s1 = pack[e + 1], s2 = pack[e + 2], s3 = pack[e + 3];
            float h0 = hs2[(size_t)s0 * 64 + lane];
            float h1 = hs2[(size_t)s1 * 64 + lane];
            float h2 = hs2[(size_t)s2 * 64 + lane];
            float h3 = hs2[(size_t)s3 * 64 + lane];
            acc += (h0 + h1) + (h2 + h3);
        }
        for (; e < end; ++e)
            acc += hs2[(size_t)pack[e] * 64 + lane];
        float val = di * (own + acc) + bb;
        int g = batch[n];
        if (g != curg) {
            atomicAdd(&pooled[curg * 64 + lane], racc);
            racc = 0.f;
            curg = g;
        }
        racc += val;
    }
    atomicAdd(&pooled[curg * 64 + lane], racc);
}

// ---------------- graph boundaries (batch sorted): start[g] per graph ----------------
__global__ __launch_bounds__(256) void bound_kernel(const int* __restrict__ batch,
                                                    int* __restrict__ start) {
    int n = blockIdx.x * 256 + threadIdx.x;
    if (n >= N_NODES) return;
    int cur  = batch[n];
    int prev = (n == 0) ? -1 : batch[n - 1];
    for (int g = prev + 1; g <= cur; ++g) start[g] = n;
    if (n == N_NODES - 1)
        for (int g = cur + 1; g <= N_GRAPHS; ++g) start[g] = N_NODES;
}

// ---------------- head: (pooled/count) @ Wl + bl ----------------
__global__ __launch_bounds__(256) void head_kernel(const float* __restrict__ pooled,
                                                   const int* __restrict__ start,
                                                   const float* __restrict__ Wl,
                                                   const float* __restrict__ bl,
                                                   float* __restrict__ out) {
    int gid = blockIdx.x * 256 + threadIdx.x;
    if (gid >= N_GRAPHS * N_CLASSES) return;
    int g = gid / N_CLASSES, c = gid % N_CLASSES;
    float cntf = (float)(start[g + 1] - start[g]);
    float inv = 1.0f / fmaxf(cntf, 1.0f);
    float acc = 0.f;
#pragma unroll
    for (int k = 0; k < OUT_CH; ++k)
        acc += pooled[g * 64 + k] * Wl[k * N_CLASSES + c];
    out[gid] = acc * inv + bl[c];
}

// ---------------- launch ----------------
extern "C" void kernel_launch(void* const* d_in, const int* in_sizes, int n_in,
                              void* d_out, int out_size, void* d_ws, size_t ws_size,
                              hipStream_t stream) {
    const float* x     = (const float*)d_in[0];
    const int*   ei    = (const int*)d_in[1];
    const int*   batch = (const int*)d_in[3];
    const float* W1    = (const float*)d_in[4];
    const float* b1    = (const float*)d_in[5];
    const float* W2    = (const float*)d_in[6];
    const float* b2    = (const float*)d_in[7];
    const float* Wl    = (const float*)d_in[8];
    const float* bl    = (const float*)d_in[9];
    float* out = (float*)d_out;

    // workspace layout (4-byte units)
    int*   wsI    = (int*)d_ws;
    int*   cnt    = wsI;                         // [0, 50048)  zeroed
    float* pooled = (float*)(wsI + 50048);       // [50048, 66432) zeroed
    int*   start  = wsI + 66432;                 // [66432, 66689)
    float* dinv   = (float*)(wsI + 66752);       // [66752, 116800)
    int*   excl   = wsI + 116800;                // [116800, 166848)
    int*   part   = wsI + 166848;                // [166848, 167104)
    int*   rs     = wsI + 167104;                // [167104, 217168) N_NODES+1
    int*   cur    = wsI + 217168;                // [217168, 267216)
    int*   pack   = wsI + 267216;                // [267216, 1067216) 800000 ints
    float* hs1    = (float*)(wsI + 1067216);     // 3.2M floats
    float* hs2    = (float*)(wsI + 4267216);     // 3.2M floats

    const int NBLK = (N_NODES + 255) / 256;      // 196

    // zero cnt + pooled
    hipMemsetAsync(wsI, 0, (size_t)66432 * sizeof(int), stream);

    // degree + CSR build (same work every call)
    deg_kernel   <<<(N_EDGES + 255) / 256, 256, 0, stream>>>(ei, cnt);
    scan1_kernel <<<NBLK, 256, 0, stream>>>(cnt, excl, part);
    scan2_kernel <<<1, 256, 0, stream>>>(part, NBLK);
    scan3_kernel <<<NBLK + 1, 256, 0, stream>>>(excl, part, cnt, rs, cur, dinv);
    bucket_kernel<<<(N_EDGES + 255) / 256, 256, 0, stream>>>(ei, cur, pack);

    // layer 1 GEMM (hs1 = x@W1 * dinv)   [50000 = 3125 * 16 exactly]
    gemm1_kernel<<<N_NODES / 16, 256, 0, stream>>>(x, W1, dinv, hs1);

    // layer 1 gather fused into layer 2 GEMM (hs2 = relu(agg1)@W2 * dinv)
    gemmgather2_kernel<<<N_NODES / 16, 256, 0, stream>>>(
        rs, pack, hs1, dinv, W2, b1, hs2);

    // layer 2 gather fused with mean-pool accumulation (4 nodes/wave)
    gatherpool_kernel<<<(N_NODES + 15) / 16, 256, 0, stream>>>(
        rs, pack, hs2, dinv, b2, batch, pooled);

    // boundaries + head
    bound_kernel<<<NBLK, 256, 0, stream>>>(batch, start);
    head_kernel <<<(N_GRAPHS * N_CLASSES + 255) / 256, 256, 0, stream>>>(
        pooled, start, Wl, bl, out);
}